// Round 9
// baseline (1113.687 us; speedup 1.0000x reference)
//
#include <hip/hip_runtime.h>
#include <cstdint>
#include <cstddef>

// Problem constants (reference: M=8192, IN=4096, OUT=4096)
#define M_DIM 8192
#define K_DIM 4096
#define N_DIM 4096

// GEMM tile geometry: 256x256 block tile, 4 waves of 128x128 each.
#define BM 256
#define BN 256
#define BK 64
#define NT (K_DIM / BK)  // 64 K-tiles

typedef unsigned short u16;
typedef __bf16 bf16x8 __attribute__((ext_vector_type(8)));
typedef u16 u16x8 __attribute__((ext_vector_type(8)));
typedef float f32x4 __attribute__((ext_vector_type(4)));

// fp32 -> bf16 round-to-nearest-even (inputs are finite normals; no NaN path)
__device__ __forceinline__ u16 f2bf_rne(float f) {
  uint32_t u = __builtin_bit_cast(uint32_t, f);
  return (u16)((u + 0x7FFFu + ((u >> 16) & 1u)) >> 16);
}
// small int -> bf16 (exact for |i| <= 8)
__device__ __forceinline__ u16 i2bf(int i) {
  return (u16)(__builtin_bit_cast(uint32_t, (float)i) >> 16);
}

#define XBLKS 16384  // M*K/8/256 blocks for the x-conversion half
#define WBLKS 8192   // N*(K/2)/4/256 blocks for the weight-dequant half

// ---- Fused prep (round-6 proven): x fp32->bf16, int4 -> bf16 int weights --
__global__ __launch_bounds__(256) void prep(const float* __restrict__ x,
                                            const int* __restrict__ wp,
                                            u16* __restrict__ xb,
                                            u16* __restrict__ wb) {
  const int b = blockIdx.x;
  if (b < XBLKS) {
    size_t t = (size_t)b * 256 + threadIdx.x;
    const float4* xp = (const float4*)x;
    float4 a = xp[2 * t];
    float4 c = xp[2 * t + 1];
    u16x8 r;
    r[0] = f2bf_rne(a.x); r[1] = f2bf_rne(a.y); r[2] = f2bf_rne(a.z); r[3] = f2bf_rne(a.w);
    r[4] = f2bf_rne(c.x); r[5] = f2bf_rne(c.y); r[6] = f2bf_rne(c.z); r[7] = f2bf_rne(c.w);
    ((u16x8*)xb)[t] = r;
  } else {
    size_t t = (size_t)(b - XBLKS) * 256 + threadIdx.x;
    int4 p = ((const int4*)wp)[t];
    u16x8 r;
    int v;
    v = p.x ^ 0x88; r[0] = i2bf((v << 28) >> 28); r[1] = i2bf((v << 24) >> 28);
    v = p.y ^ 0x88; r[2] = i2bf((v << 28) >> 28); r[3] = i2bf((v << 24) >> 28);
    v = p.z ^ 0x88; r[4] = i2bf((v << 28) >> 28); r[5] = i2bf((v << 24) >> 28);
    v = p.w ^ 0x88; r[6] = i2bf((v << 28) >> 28); r[7] = i2bf((v << 24) >> 28);
    ((u16x8*)wb)[t] = r;
  }
}

// ---- bf16 gemm_bt: 256x256 tile, 4 waves x 128x128, counted-vmcnt pipeline
// C[m][n] = (sum_k A[m][k]*B[n][k]) * scale[n] + bias[n]
//
// GEOMETRY RATIONALE: LDS frag-read traffic per wave = (Wm+Wn)*BK*2B while
// FLOPs scale with Wm*Wn. Rounds 2-6 (8 waves of 128x64) moved 192 KB of
// ds_read_b128 per CU-K-tile — at the measured ~12cyc/b128 LDS pipe rate that
// floor (~1536+ cyc) is what pinned all schedule variants at 237-260us. 4 waves
// of 128x128 cut frag traffic to 128 KB (128 reads), raising MFMA:read from
// 2.67 to 8, at the cost of 1 wave/SIMD occupancy (acc=256 VGPR; total ~380,
// under the 512 budget at launch_bounds(256,1); no spill expected <450).
//
// SYNC SKELETON (round-5/6 proven raceless, counted vmcnt, 1 barrier/tile):
// K-tile = 4 half-tiles (A0/A1 rows 0-127/128-255, B0/B1), each 128x64x2B =
// 16 KiB = 4 global_load_lds/thread (256 thr). A0 has 3 slots (T%3), A1/B0/B1
// have 2 (T&1) -> 144 KiB. Per iter T: stage A0(T+1) (its slot held A0(T-2),
// reads long retired -> safe pre-barrier) -> s_waitcnt vmcnt(4) (waits the 16
// oldest = all of tile T; never drains) -> raw s_barrier (certifies tile T
// landed everywhere AND tile T-1 reads retired -> (T+1)-parity buffers free)
// -> compute with A1/B0/B1(T+1) stages spread between MFMA clusters. Tail
// peeled with one vmcnt(0). Two sched_barrier(0) per tile (anti-hoist after
// barrier, anti-sink at end); interior is one free scheduling region with
// hand-rotated fragment loads (reads for cluster p+1 before MFMA of p).
//
// Swizzle (verified SQ_LDS_BANK_CONFLICT==0): LDS row = 64 u16 = 128 B = 32
// banks. Thread tid stages global 16B-chunk ((tid&7) ^ (srow&7)) into linear
// LDS slot tid&7 (global_load_lds needs linear dest, rule 21); readers address
// slot chunk ^ (lrow&7). Staged rows step by 32 == 0 mod 8 -> key invariant.
__global__ __launch_bounds__(256, 1) void gemm_bt_w4a16(
    const u16* __restrict__ A,      // [M_DIM, K_DIM] bf16 bits
    const u16* __restrict__ B,      // [N_DIM, K_DIM] bf16 bits (integer weights)
    const float* __restrict__ scales,
    const float* __restrict__ bias,
    float* __restrict__ C) {
  __shared__ u16 sA0[3][128 * 64];  // 48 KiB, slot = T%3
  __shared__ u16 sA1[2][128 * 64];  // 32 KiB, slot = T&1
  __shared__ u16 sB0[2][128 * 64];  // 32 KiB
  __shared__ u16 sB1[2][128 * 64];  // 32 KiB   total 144 KiB

  const int tid = threadIdx.x;
  const int lane = tid & 63;
  const int wave = tid >> 6;          // 0..3
  const int m0 = blockIdx.y * BM;
  const int n0 = blockIdx.x * BN;

  const int wm = (wave >> 1) * 128;   // 0 or 128 (2 M-waves)
  const int wn = (wave & 1) * 128;    // 0 or 128 (2 N-waves)
  const int lrow = lane & 15;         // row within a 16x16 frag
  const int quad = lane >> 4;         // k-chunk selector; m-subrow for C/D

  f32x4 acc[8][8] = {};               // 256 VGPR accumulator (128x128/wave)

  // Staging map (256 thr): thread tid covers rows srow, srow+32, srow+64,
  // srow+96 of each 128-row half (4 loads); linear chunk slot tid&7; global
  // source chunk XOR-swizzled by srow&7 (rows step by 32 == 0 mod 8).
  const int srow = tid >> 3;                    // 0..31
  const int schunk = ((tid & 7) ^ (srow & 7)) * 8;
  const u16* ga = A + (size_t)(m0 + srow) * K_DIM + schunk;
  const u16* gb = B + (size_t)(n0 + srow) * K_DIM + schunk;
  const int dst0 = tid * 16;                    // LDS byte offset; +4096/32 rows

#define GLDS(gp, lp)                                                      \
  __builtin_amdgcn_global_load_lds(                                       \
      (const __attribute__((address_space(1))) void*)(gp),                \
      (__attribute__((address_space(3))) void*)(lp), 16, 0, 0)

  // Stage one half-tile: 4 loads, rows srow + {0,32,64,96} of the half.
  auto stA0 = [&](int slot, int T) {
    const u16* g = ga + (size_t)T * BK;
    char* d = (char*)sA0[slot] + dst0;
#pragma unroll
    for (int r = 0; r < 4; ++r) GLDS(g + (size_t)(r * 32) * K_DIM, d + r * 4096);
  };
  auto stA1 = [&](int b, int T) {
    const u16* g = ga + (size_t)128 * K_DIM + (size_t)T * BK;
    char* d = (char*)sA1[b] + dst0;
#pragma unroll
    for (int r = 0; r < 4; ++r) GLDS(g + (size_t)(r * 32) * K_DIM, d + r * 4096);
  };
  auto stB0 = [&](int b, int T) {
    const u16* g = gb + (size_t)T * BK;
    char* d = (char*)sB0[b] + dst0;
#pragma unroll
    for (int r = 0; r < 4; ++r) GLDS(g + (size_t)(r * 32) * K_DIM, d + r * 4096);
  };
  auto stB1 = [&](int b, int T) {
    const u16* g = gb + (size_t)128 * K_DIM + (size_t)T * BK;
    char* d = (char*)sB1[b] + dst0;
#pragma unroll
    for (int r = 0; r < 4; ++r) GLDS(g + (size_t)(r * 32) * K_DIM, d + r * 4096);
  };

  struct frag8 { u16x8 v[8]; };

  // Prologue: tile 0 fully staged (16 loads).
  stA0(0, 0); stA1(0, 0); stB0(0, 0); stB1(0, 0);

  int a0slot = 0;  // slot of tile T's A0
#pragma unroll 1
  for (int T = 0; T < NT; ++T) {
    const int buf = T & 1;
    const int nbuf = buf ^ 1;
    const bool more = (T + 1 < NT);
    int a0next = a0slot + 1; if (a0next == 3) a0next = 0;

    if (more) {
      stA0(a0next, T + 1);                       // counted-wait enabler
      asm volatile("s_waitcnt vmcnt(4)" ::: "memory");  // tile T (16 oldest) landed
    } else {
      asm volatile("s_waitcnt vmcnt(0)" ::: "memory");  // peeled tail drain
    }
    __builtin_amdgcn_s_barrier();                // raw: young loads stay in flight
    __builtin_amdgcn_sched_barrier(0);           // anti-hoist fence

    const u16* aH = (wm == 0) ? sA0[a0slot] : sA1[buf];
    const u16* bH = (wn == 0) ? sB0[buf] : sB1[buf];

    const int kc0 = ((0 * 4 + quad) ^ (lrow & 7)) * 8;
    const int kc1 = ((1 * 4 + quad) ^ (lrow & 7)) * 8;

    auto ldA8 = [&](int kc) {
      frag8 f;
#pragma unroll
      for (int i = 0; i < 8; ++i)
        f.v[i] = *(const u16x8*)(aH + (i * 16 + lrow) * BK + kc);
      return f;
    };
    auto ldB8 = [&](int kc) {
      frag8 f;
#pragma unroll
      for (int j = 0; j < 8; ++j)
        f.v[j] = *(const u16x8*)(bH + (j * 16 + lrow) * BK + kc);
      return f;
    };

    // Rotated-fragment schedule: reads for cluster p+1 issue before MFMA of
    // p; one half-tile stage per cluster boundary. 4 clusters x 32 MFMA.
    frag8 fa0 = ldA8(kc0);
    frag8 fb0 = ldB8(kc0);

    if (more) stA1(nbuf, T + 1);
    __builtin_amdgcn_s_setprio(1);
#pragma unroll
    for (int i = 0; i < 4; ++i)
#pragma unroll
      for (int j = 0; j < 8; ++j)
        acc[i][j] = __builtin_amdgcn_mfma_f32_16x16x32_bf16(
            __builtin_bit_cast(bf16x8, fa0.v[i]),
            __builtin_bit_cast(bf16x8, fb0.v[j]), acc[i][j], 0, 0, 0);
    __builtin_amdgcn_s_setprio(0);

    frag8 fa1 = ldA8(kc1);                       // prefetch kc1 A
    if (more) stB0(nbuf, T + 1);
    __builtin_amdgcn_s_setprio(1);
#pragma unroll
    for (int i = 0; i < 4; ++i)
#pragma unroll
      for (int j = 0; j < 8; ++j)
        acc[4 + i][j] = __builtin_amdgcn_mfma_f32_16x16x32_bf16(
            __builtin_bit_cast(bf16x8, fa0.v[4 + i]),
            __builtin_bit_cast(bf16x8, fb0.v[j]), acc[4 + i][j], 0, 0, 0);
    __builtin_amdgcn_s_setprio(0);

    frag8 fb1 = ldB8(kc1);                       // prefetch kc1 B
    if (more) stB1(nbuf, T + 1);
    __builtin_amdgcn_s_setprio(1);
#pragma unroll
    for (int i = 0; i < 4; ++i)
#pragma unroll
      for (int j = 0; j < 8; ++j)
        acc[i][j] = __builtin_amdgcn_mfma_f32_16x16x32_bf16(
            __builtin_bit_cast(bf16x8, fa1.v[i]),
            __builtin_bit_cast(bf16x8, fb1.v[j]), acc[i][j], 0, 0, 0);
    __builtin_amdgcn_s_setprio(0);

    __builtin_amdgcn_s_setprio(1);
#pragma unroll
    for (int i = 0; i < 4; ++i)
#pragma unroll
      for (int j = 0; j < 8; ++j)
        acc[4 + i][j] = __builtin_amdgcn_mfma_f32_16x16x32_bf16(
            __builtin_bit_cast(bf16x8, fa1.v[4 + i]),
            __builtin_bit_cast(bf16x8, fb1.v[j]), acc[4 + i][j], 0, 0, 0);
    __builtin_amdgcn_s_setprio(0);

    __builtin_amdgcn_sched_barrier(0);           // anti-sink fence (tile ends)
    a0slot = a0next;
  }

  // Epilogue: C/D layout col = lane&15 (n), row = quad*4 + reg (m). Apply
  // per-output-row scale + bias here (keeps MFMA inputs exact integers).
#pragma unroll
  for (int j = 0; j < 8; ++j) {
    const int n = n0 + wn + j * 16 + lrow;
    const float sc = scales[n];
    const float bi = bias[n];
#pragma unroll
    for (int i = 0; i < 8; ++i) {
      const int m = m0 + wm + i * 16 + quad * 4;
      float* cp = &C[(size_t)m * N_DIM + n];
#pragma unroll
      for (int r = 0; r < 4; ++r)
        cp[(size_t)r * N_DIM] = acc[i][j][r] * sc + bi;
    }
  }
#undef GLDS
}

// ---------------- Fallback (ws too small): fp32 direct, correct but slow ----
__global__ __launch_bounds__(256) void fallback_w4a16(
    const float* __restrict__ x, const int* __restrict__ wp,
    const float* __restrict__ scales, const float* __restrict__ bias,
    float* __restrict__ out) {
  const int n = blockIdx.x * 256 + threadIdx.x;
  const int m = blockIdx.y;
  const float* xr = x + (size_t)m * K_DIM;
  const int* wr = wp + (size_t)n * (K_DIM / 2);
  float acc = 0.f;
  for (int j = 0; j < K_DIM / 2; ++j) {
    int w = wr[j] ^ 0x88;
    float lo = (float)((w << 28) >> 28);
    float hi = (float)((w << 24) >> 28);
    acc += xr[2 * j] * lo + xr[2 * j + 1] * hi;
  }
  out[(size_t)m * N_DIM + n] = acc * scales[n] + bias[n];
}

extern "C" void kernel_launch(void* const* d_in, const int* in_sizes, int n_in,
                              void* d_out, int out_size, void* d_ws, size_t ws_size,
                              hipStream_t stream) {
  const float* x = (const float*)d_in[0];
  const int* wp = (const int*)d_in[1];
  const float* sc = (const float*)d_in[2];
  const float* bi = (const float*)d_in[3];
  float* out = (float*)d_out;

  const size_t xb_elems = (size_t)M_DIM * K_DIM;           // 64 MiB as u16
  const size_t wb_elems = (size_t)N_DIM * K_DIM;           // 32 MiB as u16
  const size_t need = (xb_elems + wb_elems) * sizeof(u16); // 100,663,296 B

  if (ws_size >= need) {
    u16* xb = (u16*)d_ws;
    u16* wb = xb + xb_elems;
    prep<<<XBLKS + WBLKS, 256, 0, stream>>>(x, wp, xb, wb);
    gemm_bt_w4a16<<<dim3(N_DIM / BN, M_DIM / BM), 256, 0, stream>>>(xb, wb, sc, bi, out);
  } else {
    fallback_w4a16<<<dim3(N_DIM / 256, M_DIM), 256, 0, stream>>>(x, wp, sc, bi, out);
  }
}

// Round 10
// 493.187 us; speedup vs baseline: 2.2581x; 2.2581x over previous
//
#include <hip/hip_runtime.h>
#include <cstdint>
#include <cstddef>

// Problem constants (reference: M=8192, IN=4096, OUT=4096)
#define M_DIM 8192
#define K_DIM 4096
#define N_DIM 4096

// GEMM tile geometry
#define BM 256
#define BN 256
#define BK 64
#define NT (K_DIM / BK)  // 64 K-tiles

typedef unsigned short u16;
typedef __bf16 bf16x8 __attribute__((ext_vector_type(8)));
typedef u16 u16x8 __attribute__((ext_vector_type(8)));
typedef float f32x16 __attribute__((ext_vector_type(16)));

// fp32 -> bf16 round-to-nearest-even (inputs are finite normals; no NaN path)
__device__ __forceinline__ u16 f2bf_rne(float f) {
  uint32_t u = __builtin_bit_cast(uint32_t, f);
  return (u16)((u + 0x7FFFu + ((u >> 16) & 1u)) >> 16);
}
// small int -> bf16 (exact for |i| <= 8)
__device__ __forceinline__ u16 i2bf(int i) {
  return (u16)(__builtin_bit_cast(uint32_t, (float)i) >> 16);
}

#define XBLKS 16384  // M*K/8/256 blocks for the x-conversion half
#define WBLKS 8192   // N*(K/2)/4/256 blocks for the weight-dequant half

// ---- Fused prep (round-6 proven): x fp32->bf16, int4 -> bf16 int weights --
__global__ __launch_bounds__(256) void prep(const float* __restrict__ x,
                                            const int* __restrict__ wp,
                                            u16* __restrict__ xb,
                                            u16* __restrict__ wb) {
  const int b = blockIdx.x;
  if (b < XBLKS) {
    size_t t = (size_t)b * 256 + threadIdx.x;
    const float4* xp = (const float4*)x;
    float4 a = xp[2 * t];
    float4 c = xp[2 * t + 1];
    u16x8 r;
    r[0] = f2bf_rne(a.x); r[1] = f2bf_rne(a.y); r[2] = f2bf_rne(a.z); r[3] = f2bf_rne(a.w);
    r[4] = f2bf_rne(c.x); r[5] = f2bf_rne(c.y); r[6] = f2bf_rne(c.z); r[7] = f2bf_rne(c.w);
    ((u16x8*)xb)[t] = r;
  } else {
    size_t t = (size_t)(b - XBLKS) * 256 + threadIdx.x;
    int4 p = ((const int4*)wp)[t];
    u16x8 r;
    int v;
    v = p.x ^ 0x88; r[0] = i2bf((v << 28) >> 28); r[1] = i2bf((v << 24) >> 28);
    v = p.y ^ 0x88; r[2] = i2bf((v << 28) >> 28); r[3] = i2bf((v << 24) >> 28);
    v = p.z ^ 0x88; r[4] = i2bf((v << 28) >> 28); r[5] = i2bf((v << 24) >> 28);
    v = p.w ^ 0x88; r[6] = i2bf((v << 28) >> 28); r[7] = i2bf((v << 24) >> 28);
    ((u16x8*)wb)[t] = r;
  }
}

// ---- bf16 gemm_bt: 256x256 tile, 8 waves x 128x64, 32x32x16 MFMA ----------
// C[m][n] = (sum_k A[m][k]*B[n][k]) * scale[n] + bias[n]
//
// ROUND-10 CHANGE (only): MFMA shape 16x16x32 -> 32x32x16. m119: 32x32 pipe
// sustains 4060 FLOP/cyc/CU vs 16x16's 3378 (+20%); per-CU MFMA floor per
// K-tile drops 2483 -> 2066 cyc, and instruction count halves (64 -> 32 per
// wave-tile). LDS frag traffic unchanged (24 x ds_read_b128 / wave / tile).
// Fragment layouts: A row = lane&31, k = (lane>>5)*8+e (generalizes the
// verified 16x16 mapping); B symmetric (col = lane&31); C/D col = lane&31,
// row = (reg&3) + 8*(reg>>2) + 4*(lane>>5) [HW-verified m74/m101].
// Round-9 lesson: 128x128/wave spills (VGPR cap 256, 2 GB scratch) — stay at
// 128x64/wave where acc = 128 regs fits in AGPRs (round-6 VGPR_Count = 112).
//
// SYNC SKELETON (round-5/6 proven raceless, counted vmcnt, 1 barrier/tile):
// K-tile = 4 half-tiles (A0/A1 rows 0-127/128-255, B0/B1), each 128x64x2B =
// 16 KiB = 2 global_load_lds/thread (512 thr). A0 has 3 slots (T%3), A1/B0/B1
// have 2 (T&1) -> 144 KiB. Per iter T: stage A0(T+1) (its slot held A0(T-2),
// reads long retired -> safe pre-barrier) -> s_waitcnt vmcnt(2) (waits the 8
// oldest = all of tile T; never drains) -> raw s_barrier (certifies tile T
// landed everywhere AND tile T-1 reads retired -> (T+1)-parity buffers free)
// -> compute with A1/B0/B1(T+1) stages spread between MFMA clusters. Tail
// peeled with one vmcnt(0). Two sched_barrier(0) per tile (anti-hoist after
// barrier, anti-sink at end); interior is one free scheduling region with
// rotated fragment loads (reads for cluster p+1 issue before MFMA of p).
//
// Swizzle (verified SQ_LDS_BANK_CONFLICT==0): LDS row = 64 u16 = 128 B = 32
// banks. Thread tid stages global 16B-chunk ((tid&7) ^ (srow&7)) into linear
// LDS slot tid&7 (global_load_lds needs linear dest, rule 21); readers address
// slot chunk ^ (row&7). Staged rows step by 64 == 0 mod 8 -> key invariant;
// reader key = lane&7 (row bases all == 0 mod 8).
__global__ __launch_bounds__(512, 2) void gemm_bt_w4a16(
    const u16* __restrict__ A,      // [M_DIM, K_DIM] bf16 bits
    const u16* __restrict__ B,      // [N_DIM, K_DIM] bf16 bits (integer weights)
    const float* __restrict__ scales,
    const float* __restrict__ bias,
    float* __restrict__ C) {
  __shared__ u16 sA0[3][128 * 64];  // 48 KiB, slot = T%3
  __shared__ u16 sA1[2][128 * 64];  // 32 KiB, slot = T&1
  __shared__ u16 sB0[2][128 * 64];  // 32 KiB
  __shared__ u16 sB1[2][128 * 64];  // 32 KiB   total 144 KiB

  const int tid = threadIdx.x;
  const int lane = tid & 63;
  const int wave = tid >> 6;          // 0..7
  const int m0 = blockIdx.y * BM;
  const int n0 = blockIdx.x * BN;

  const int wm = (wave >> 2) * 128;   // 0 or 128   (2 M-waves)
  const int wn = (wave & 3) * 64;     // 0,64,128,192 (4 N-waves)
  const int brw0 = wn & 64;           // B row base within its half

  // 32x32x16 fragment lane decomposition
  const int arow = lane & 31;         // M (A) or N (B) index within a 32-tile
  const int kq = lane >> 5;           // k-chunk (8 elems) selector within K=16
  const int key = lane & 7;           // swizzle key (row bases == 0 mod 8)

  f32x16 acc[4][2] = {};              // 128 regs: 4 m-tiles x 2 n-tiles of 32x32

  // Staging map: thread tid covers half-rows srow and srow+64 (2 loads),
  // linear chunk slot tid&7; global source chunk XOR-swizzled by srow&7.
  const int srow = tid >> 3;                    // 0..63
  const int schunk = ((tid & 7) ^ (srow & 7)) * 8;
  const u16* ga = A + (size_t)(m0 + srow) * K_DIM + schunk;  // A half0 row srow
  const u16* gb = B + (size_t)(n0 + srow) * K_DIM + schunk;
  const int dst0 = tid * 16;                    // LDS byte offset; +8192 for row+64

#define GLDS(gp, lp)                                                      \
  __builtin_amdgcn_global_load_lds(                                       \
      (const __attribute__((address_space(1))) void*)(gp),                \
      (__attribute__((address_space(3))) void*)(lp), 16, 0, 0)

  // Stage one half-tile (2 loads: rows srow and srow+64 of the half).
  auto stA0 = [&](int slot, int T) {
    const u16* g = ga + (size_t)T * BK;
    char* d = (char*)sA0[slot] + dst0;
    GLDS(g, d);
    GLDS(g + (size_t)64 * K_DIM, d + 8192);
  };
  auto stA1 = [&](int b, int T) {
    const u16* g = ga + (size_t)128 * K_DIM + (size_t)T * BK;
    char* d = (char*)sA1[b] + dst0;
    GLDS(g, d);
    GLDS(g + (size_t)64 * K_DIM, d + 8192);
  };
  auto stB0 = [&](int b, int T) {
    const u16* g = gb + (size_t)T * BK;
    char* d = (char*)sB0[b] + dst0;
    GLDS(g, d);
    GLDS(g + (size_t)64 * K_DIM, d + 8192);
  };
  auto stB1 = [&](int b, int T) {
    const u16* g = gb + (size_t)128 * K_DIM + (size_t)T * BK;
    char* d = (char*)sB1[b] + dst0;
    GLDS(g, d);
    GLDS(g + (size_t)64 * K_DIM, d + 8192);
  };

  struct fragA { u16x8 v[4]; };
  struct fragB { u16x8 v[2]; };

  // Prologue: tile 0 fully staged (8 loads).
  stA0(0, 0); stA1(0, 0); stB0(0, 0); stB1(0, 0);

  int a0slot = 0;  // slot of tile T's A0
#pragma unroll 1
  for (int T = 0; T < NT; ++T) {
    const int buf = T & 1;
    const int nbuf = buf ^ 1;
    const bool more = (T + 1 < NT);
    int a0next = a0slot + 1; if (a0next == 3) a0next = 0;

    if (more) {
      stA0(a0next, T + 1);                       // counted-wait enabler
      asm volatile("s_waitcnt vmcnt(2)" ::: "memory");  // tile T (8 oldest) landed
    } else {
      asm volatile("s_waitcnt vmcnt(0)" ::: "memory");  // peeled tail drain
    }
    __builtin_amdgcn_s_barrier();                // raw: young loads stay in flight
    __builtin_amdgcn_sched_barrier(0);           // anti-hoist fence

    const u16* aH = (wave < 4) ? sA0[a0slot] : sA1[buf];
    const u16* bH = (wn < 128) ? sB0[buf] : sB1[buf];

    // ks = one K=16 slice (2 chunks of 8); 4 slices per K-tile.
    auto ldA = [&](int ks) {
      fragA f;
      const int sl = ((ks * 2 + kq) ^ key) * 8;
#pragma unroll
      for (int t = 0; t < 4; ++t)
        f.v[t] = *(const u16x8*)(aH + (t * 32 + arow) * BK + sl);
      return f;
    };
    auto ldB = [&](int ks) {
      fragB f;
      const int sl = ((ks * 2 + kq) ^ key) * 8;
#pragma unroll
      for (int t = 0; t < 2; ++t)
        f.v[t] = *(const u16x8*)(bH + (brw0 + t * 32 + arow) * BK + sl);
      return f;
    };

#define CLUSTER(fa, fb)                                                   \
  __builtin_amdgcn_s_setprio(1);                                          \
  _Pragma("unroll")                                                       \
  for (int tm = 0; tm < 4; ++tm)                                          \
    _Pragma("unroll")                                                     \
    for (int tn = 0; tn < 2; ++tn)                                        \
      acc[tm][tn] = __builtin_amdgcn_mfma_f32_32x32x16_bf16(              \
          __builtin_bit_cast(bf16x8, fa.v[tm]),                           \
          __builtin_bit_cast(bf16x8, fb.v[tn]), acc[tm][tn], 0, 0, 0);    \
  __builtin_amdgcn_s_setprio(0);

    // Rotated schedule: reads for cluster p+1 issue before MFMA of p; one
    // half-tile stage per cluster boundary. 4 clusters x 8 MFMA(32x32x16).
    fragA fa0 = ldA(0); fragB fb0 = ldB(0);
    fragA fa1 = ldA(1); fragB fb1 = ldB(1);
    if (more) stA1(nbuf, T + 1);
    CLUSTER(fa0, fb0);

    fragA fa2 = ldA(2); fragB fb2 = ldB(2);
    if (more) stB0(nbuf, T + 1);
    CLUSTER(fa1, fb1);

    fragA fa3 = ldA(3); fragB fb3 = ldB(3);
    if (more) stB1(nbuf, T + 1);
    CLUSTER(fa2, fb2);

    CLUSTER(fa3, fb3);
#undef CLUSTER

    __builtin_amdgcn_sched_barrier(0);           // anti-sink fence (tile ends)
    a0slot = a0next;
  }

  // Epilogue: 32x32 C/D layout col = lane&31 (n), row = (reg&3) + 8*(reg>>2)
  // + 4*(lane>>5) (m) [HW-verified m74/m101]. Apply per-output-row scale +
  // bias here (keeps MFMA inputs exact integers).
#pragma unroll
  for (int tn = 0; tn < 2; ++tn) {
    const int n = n0 + wn + tn * 32 + arow;
    const float sc = scales[n];
    const float bi = bias[n];
#pragma unroll
    for (int tm = 0; tm < 4; ++tm) {
      const int mb = m0 + wm + tm * 32 + 4 * kq;
#pragma unroll
      for (int r = 0; r < 16; ++r) {
        const int m = mb + (r & 3) + 8 * (r >> 2);
        C[(size_t)m * N_DIM + n] = acc[tm][tn][r] * sc + bi;
      }
    }
  }
#undef GLDS
}

// ---------------- Fallback (ws too small): fp32 direct, correct but slow ----
__global__ __launch_bounds__(256) void fallback_w4a16(
    const float* __restrict__ x, const int* __restrict__ wp,
    const float* __restrict__ scales, const float* __restrict__ bias,
    float* __restrict__ out) {
  const int n = blockIdx.x * 256 + threadIdx.x;
  const int m = blockIdx.y;
  const float* xr = x + (size_t)m * K_DIM;
  const int* wr = wp + (size_t)n * (K_DIM / 2);
  float acc = 0.f;
  for (int j = 0; j < K_DIM / 2; ++j) {
    int w = wr[j] ^ 0x88;
    float lo = (float)((w << 28) >> 28);
    float hi = (float)((w << 24) >> 28);
    acc += xr[2 * j] * lo + xr[2 * j + 1] * hi;
  }
  out[(size_t)m * N_DIM + n] = acc * scales[n] + bias[n];
}

extern "C" void kernel_launch(void* const* d_in, const int* in_sizes, int n_in,
                              void* d_out, int out_size, void* d_ws, size_t ws_size,
                              hipStream_t stream) {
  const float* x = (const float*)d_in[0];
  const int* wp = (const int*)d_in[1];
  const float* sc = (const float*)d_in[2];
  const float* bi = (const float*)d_in[3];
  float* out = (float*)d_out;

  const size_t xb_elems = (size_t)M_DIM * K_DIM;           // 64 MiB as u16
  const size_t wb_elems = (size_t)N_DIM * K_DIM;           // 32 MiB as u16
  const size_t need = (xb_elems + wb_elems) * sizeof(u16); // 100,663,296 B

  if (ws_size >= need) {
    u16* xb = (u16*)d_ws;
    u16* wb = xb + xb_elems;
    prep<<<XBLKS + WBLKS, 256, 0, stream>>>(x, wp, xb, wb);
    gemm_bt_w4a16<<<dim3(N_DIM / BN, M_DIM / BM), 512, 0, stream>>>(xb, wb, sc, bi, out);
  } else {
    fallback_w4a16<<<dim3(N_DIM / 256, M_DIM), 256, 0, stream>>>(x, wp, sc, bi, out);
  }
}